// Round 15
// baseline (202.195 us; speedup 1.0000x reference)
//
#include <hip/hip_runtime.h>
#include <math.h>

#define NB 4
#define CD 384
#define CM 1536
#define HIDC 128
#define HRES 448
#define NSEG 64
#define LNN (CM*1024)
#define PPX 1156                 // 34*34 padded plane
#define KSTR ((size_t)3*NB*128*1024)   // sacc per-ksplit stride

typedef unsigned short bf16_t;
typedef __attribute__((ext_vector_type(8))) short s16x8;
typedef __attribute__((ext_vector_type(4))) short s16x4;
typedef __attribute__((ext_vector_type(4))) float f32x4;

__device__ inline bf16_t f2bf(float v) {
  unsigned int x = __float_as_uint(v);
  unsigned int r = (x + 0x7fffu + ((x >> 16) & 1u)) >> 16;  // RNE, finite
  return (bf16_t)r;
}
__device__ inline float bf2f(bf16_t u) {
  return __uint_as_float(((unsigned int)u) << 16);
}

// ================= merged front: seg | fold3b | ln0 ========================
__device__ void seg_body(int c, int b, int t,
                         const float* __restrict__ fsem, const int* __restrict__ seg,
                         float* __restrict__ sums, float* __restrict__ cnt) {
  __shared__ float ssum[NSEG];
  __shared__ float scnt[NSEG];
  if (t < NSEG) { ssum[t] = 0.f; scnt[t] = 0.f; }
  __syncthreads();
  const float* f = fsem + ((size_t)b*CD + c)*1024;
  const int* sg = seg + (size_t)b*HRES*HRES;
  #pragma unroll
  for (int i = 0; i < 4; i++) {
    int p = i*256 + t;
    int py = p >> 5, px = p & 31;
    int id = sg[14*py*HRES + 14*px];
    id = min(max(id, 0), NSEG-1);
    atomicAdd(&ssum[id], f[p]);
    if (c == 0) atomicAdd(&scnt[id], 1.f);
  }
  __syncthreads();
  if (t < NSEG) {
    sums[((size_t)b*NSEG + t)*CD + c] = ssum[t];
    if (c == 0) cnt[b*NSEG + t] = scnt[t];
  }
}

__device__ void fold3b_body(int bx, int ks, int t,
                            const float* __restrict__ w0, const float* __restrict__ wb,
                            const float* __restrict__ bb, const float* __restrict__ b0v,
                            const float* s0bs, const float* s1bs, const float* s2bs,
                            const float* s0bg, const float* s1bg, const float* s1bb,
                            const float* s2bg, const float* s2bb,
                            float* __restrict__ wbfp, float* __restrict__ bextp,
                            float* biasS, float* biasG0, float* biasG1, float* biasG2) {
  if (bx == 6) {
    if (ks != 0) return;
    for (int i = t; i < 128; i += 256) {
      biasS[i] = s0bs[i]; biasS[128+i] = s1bs[i]; biasS[256+i] = s2bs[i];
    }
    for (int i = t; i < 1664; i += 256) biasG0[i] = (i < 1536) ? s0bg[i] : 0.f;
    if (t < 16) biasG1[t] = (t < 8) ? s1bg[t] : s1bb[t-8];
    if (t < 32) biasG2[t] = (t < 16) ? s2bg[t] : s2bb[t-16];
    return;
  }
  int c0 = ks*48;
  if (bx < 5) {
    int jk = bx*256 + t;
    if (jk >= 1152) return;
    float acc[8];
    #pragma unroll
    for (int o = 0; o < 8; o++) acc[o] = 0.f;
    for (int c = c0; c < c0 + 48; c++) {
      float wv = wb[(size_t)c*1152 + jk];
      #pragma unroll
      for (int o = 0; o < 8; o++) acc[o] = fmaf(w0[o*CM + c], wv, acc[o]);
    }
    #pragma unroll
    for (int o = 0; o < 8; o++) wbfp[((size_t)ks*8 + o)*1152 + jk] = acc[o];
  } else {
    if (t < 8) {
      float s = (ks == 0) ? b0v[t] : 0.f;
      for (int c = c0; c < c0 + 48; c++) s = fmaf(w0[t*CM + c], bb[c], s);
      bextp[ks*8 + t] = s;
    }
  }
}

__device__ void ln0_body(int cx, int b, int t,
                         const float* __restrict__ x, float* __restrict__ lnp) {
  const int CHUNK = LNN/64;
  const f32x4* xb = (const f32x4*)(x + (size_t)b*LNN + (size_t)cx*CHUNK);
  float s = 0.f, q = 0.f;
  for (int i = t; i < CHUNK/4; i += 256) {
    f32x4 v = xb[i];
    s += v[0] + v[1] + v[2] + v[3];
    q = fmaf(v[0],v[0], fmaf(v[1],v[1], fmaf(v[2],v[2], fmaf(v[3],v[3], q))));
  }
  __shared__ float rs[256], rq[256];
  rs[t] = s; rq[t] = q;
  __syncthreads();
  for (int st = 128; st > 0; st >>= 1) {
    if (t < st) { rs[t] += rs[t+st]; rq[t] += rq[t+st]; }
    __syncthreads();
  }
  if (t == 0) {
    lnp[(b*64 + cx)*2]     = rs[0];
    lnp[(b*64 + cx)*2 + 1] = rq[0];
  }
}

__global__ __launch_bounds__(256) void k_front(
    const float* fsem, const int* seg, float* sums, float* cnt,
    const float* w0, const float* wb, const float* bb, const float* b0v,
    const float* s0bs, const float* s1bs, const float* s2bs,
    const float* s0bg, const float* s1bg, const float* s1bb,
    const float* s2bg, const float* s2bb,
    float* wbfp, float* bextp,
    float* biasS, float* biasG0, float* biasG1, float* biasG2,
    const float* x, float* lnp) {
  int L = blockIdx.x, t = threadIdx.x;
  if (L < 1536) {
    seg_body(L % 384, L / 384, t, fsem, seg, sums, cnt);
  } else if (L < 1760) {
    int i2 = L - 1536;
    fold3b_body(i2 % 7, i2 / 7, t, w0, wb, bb, b0v,
                s0bs, s1bs, s2bs, s0bg, s1bg, s1bb, s2bg, s2bb,
                wbfp, bextp, biasS, biasG0, biasG1, biasG2);
  } else {
    int i3 = L - 1760;
    ln0_body(i3 & 63, i3 >> 6, t, x, lnp);
  }
}

// ================= merged mid: paint | packall =============================
__device__ void paint_body(int oyp, int b, int t,
                           const float* __restrict__ sums, const float* __restrict__ cnt,
                           const int* __restrict__ seg, bf16_t* __restrict__ smP) {
  __shared__ int sid[32][4];
  __shared__ float sinv[32][4];
  bool border_row = (oyp == 0 || oyp == 33);
  if (!border_row && t < 32) {
    int oy = oyp - 1;
    const int* sg = seg + (size_t)b*HRES*HRES;
    int y0 = 14*oy + 6, x0 = 14*t + 6;
    int ids[4];
    ids[0] = sg[y0*HRES + x0];     ids[1] = sg[y0*HRES + x0 + 1];
    ids[2] = sg[(y0+1)*HRES + x0]; ids[3] = sg[(y0+1)*HRES + x0 + 1];
    #pragma unroll
    for (int k = 0; k < 4; k++) {
      int id = min(max(ids[k], 0), NSEG-1);
      sid[t][k] = id;
      float c = cnt[b*NSEG + id];
      sinv[t][k] = (c > 0.f) ? 1.f/c : 0.f;
    }
  }
  __syncthreads();
  const float* sb = sums + (size_t)b*NSEG*CD;
  for (int i = t; i < 34*CD; i += 256) {
    int c = i % CD;
    int xp = i / CD;
    float v = 0.f;
    if (!border_row && xp != 0 && xp != 33) {
      int ox = xp - 1;
      v = 0.25f*(sinv[ox][0]*sb[sid[ox][0]*CD + c] + sinv[ox][1]*sb[sid[ox][1]*CD + c]
               + sinv[ox][2]*sb[sid[ox][2]*CD + c] + sinv[ox][3]*sb[sid[ox][3]*CD + c]);
    }
    smP[(((size_t)b*12 + (c>>5))*PPX + oyp*34 + xp)*32 + (c&31)] = f2bf(v);
  }
}

__device__ void packall_body(int bx, int cfg, int t,
    const float* s0_ws, const float* s1_ws, const float* s2_ws,
    const float* s0_wg, const float* wbfp,
    const float* s1_wg, const float* s1_wb,
    const float* s2_wg, const float* s2_wb,
    bf16_t* wpkS, bf16_t* wpkG0, bf16_t* wpkG1, bf16_t* wpkG2) {
  const float* wA; const float* wB; int OA, OBn, I, obT, CBn; bf16_t* dst;
  switch (cfg) {
    case 0: wA=s0_ws; wB=nullptr; OA=128;  OBn=0;  I=384; obT=8;   CBn=12; dst=wpkS;          break;
    case 1: wA=s1_ws; wB=nullptr; OA=128;  OBn=0;  I=384; obT=8;   CBn=12; dst=wpkS+442368;   break;
    case 2: wA=s2_ws; wB=nullptr; OA=128;  OBn=0;  I=384; obT=8;   CBn=12; dst=wpkS+884736;   break;
    case 3: wA=s0_wg; wB=wbfp;    OA=1536; OBn=8;  I=128; obT=104; CBn=4;  dst=wpkG0;         break;
    case 4: wA=s1_wg; wB=s1_wb;   OA=8;    OBn=8;  I=128; obT=4;   CBn=4;  dst=wpkG1;         break;
    default:wA=s2_wg; wB=s2_wb;   OA=16;   OBn=16; I=128; obT=4;   CBn=4;  dst=wpkG2;         break;
  }
  size_t idx = (size_t)bx*256 + t;
  size_t tot = (size_t)9*CBn*obT*64;
  if (idx >= tot) return;
  int lane = idx & 63;
  size_t q = idx >> 6;
  int ob = q % obT; q /= obT;
  int cb = q % CBn;
  int tap = q / CBn;
  int o = ob*16 + (lane & 15);
  int ib = cb*32 + ((lane >> 4) << 3);
  s16x8 vv;
  #pragma unroll
  for (int j = 0; j < 8; j++) {
    int i = ib + j;
    float v = 0.f;
    if (o < OA) v = wA[((size_t)o*I + i)*9 + tap];
    else if (o - OA < OBn) {
      if (cfg == 3) {
        float s = 0.f;
        for (int ks = 0; ks < 32; ks++)
          s += wB[((size_t)ks*8 + (o - OA))*1152 + i*9 + tap];
        v = s;
      } else {
        v = wB[((size_t)(o-OA)*I + i)*9 + tap];
      }
    }
    vv[j] = (short)f2bf(v);
  }
  *(s16x8*)(dst + idx*8) = vv;
}

__global__ __launch_bounds__(256) void k_mid(
    const float* sums, const float* cnt, const int* seg, bf16_t* smP,
    const float* s0_ws, const float* s1_ws, const float* s2_ws,
    const float* s0_wg, const float* wbfp,
    const float* s1_wg, const float* s1_wb,
    const float* s2_wg, const float* s2_wb,
    bf16_t* wpkS, bf16_t* wpkG0, bf16_t* wpkG1, bf16_t* wpkG2) {
  int L = blockIdx.x, t = threadIdx.x;
  if (L < 136) {
    paint_body(L % 34, L / 34, t, sums, cnt, seg, smP);
  } else {
    int i2 = L - 136;
    packall_body(i2 % 936, i2 / 936, t,
                 s0_ws, s1_ws, s2_ws, s0_wg, wbfp, s1_wg, s1_wb, s2_wg, s2_wb,
                 wpkS, wpkG0, wpkG1, wpkG2);
  }
}

// ---- shared-B LDS staging: layout [cb][row3][koff4][px34][8 bf16] ---------
#define STAGE_B(ldsbuf, inRegion, R) do { \
    for (int i = t; i < 1632; i += 256) { \
      int c_ = i & 3; \
      int q_ = i >> 2; \
      int px_ = q_ % 34; \
      int r2_ = q_ / 34; \
      int row_ = r2_ % 3; \
      int cb_ = r2_ / 3; \
      *(s16x8*)(ldsbuf + (((cb_*3 + row_)*4 + c_)*34 + px_)*8) = \
        *(const s16x8*)((inRegion) + ((size_t)cb_*PPX + ((R) + row_)*34 + px_)*32 + c_*8); \
    } \
  } while (0)

// XCD z-colocation decode: blocks with same z share (blockIdx % 8) -> one XCD L2
#define XCD_DECODE(z, R, b) do { \
    int L_ = blockIdx.x; \
    if (L_ < 1024) { z = L_ & 7; int j_ = L_ >> 3; R = j_ & 31; b = j_ >> 5; } \
    else { int j_ = L_ - 1024; z = 8; R = j_ & 31; b = j_ >> 5; } \
  } while (0)

// ---------------- conv_s: K-split x3, shared-B LDS, 4-deep A pipeline ------
__global__ __launch_bounds__(256, 4) void k_convS(
    const bf16_t* __restrict__ smP, const bf16_t* __restrict__ wpkS,
    float* __restrict__ sacc) {
  int z, R, b;
  XCD_DECODE(z, R, b);
  int cid = z/3, ks = z - cid*3;
  int t = threadIdx.x, lane = t & 63, w = t >> 6;
  int cb0 = ks*4;
  const bf16_t* wpk = wpkS + (size_t)cid*442368;
  const bf16_t* inRegion = smP + ((size_t)b*12 + cb0)*(PPX*32);

  __shared__ bf16_t lds[13056];
  STAGE_B(lds, inRegion, R);
  __syncthreads();

  int koff = lane >> 4;
  int pxc0 = lane & 15, pxc1 = 16 + (lane & 15);
  auto afp = [&](int tp, int jj, int mi) {
    return wpk + (size_t)((tp*12 + cb0 + jj)*8 + w*2 + mi)*512 + lane*8;
  };
  auto blds = [&](int tp, int jj, int pxc) {
    return lds + (((jj*3 + tp/3)*4 + koff)*34 + pxc + tp%3)*8;
  };
  f32x4 acc[2][2];
  #pragma unroll
  for (int mi = 0; mi < 2; ++mi)
    #pragma unroll
    for (int ni = 0; ni < 2; ++ni) acc[mi][ni] = (f32x4){0.f,0.f,0.f,0.f};

  s16x8 A[4][2];
  #define LDA_S(buf, s) do { const int tp=(s)>>2, jj=(s)&3; \
      A[buf][0]=*(const s16x8*)afp(tp,jj,0); A[buf][1]=*(const s16x8*)afp(tp,jj,1); } while(0)
  LDA_S(0, 0); LDA_S(1, 1); LDA_S(2, 2); LDA_S(3, 3);
  #pragma unroll
  for (int s = 0; s < 36; ++s) {
    const int tp = s >> 2, jj = s & 3, buf = s & 3;
    s16x8 B0 = *(const s16x8*)blds(tp, jj, pxc0);
    s16x8 B1 = *(const s16x8*)blds(tp, jj, pxc1);
    acc[0][0] = __builtin_amdgcn_mfma_f32_16x16x32_bf16(A[buf][0], B0, acc[0][0], 0,0,0);
    acc[0][1] = __builtin_amdgcn_mfma_f32_16x16x32_bf16(A[buf][0], B1, acc[0][1], 0,0,0);
    acc[1][0] = __builtin_amdgcn_mfma_f32_16x16x32_bf16(A[buf][1], B0, acc[1][0], 0,0,0);
    acc[1][1] = __builtin_amdgcn_mfma_f32_16x16x32_bf16(A[buf][1], B1, acc[1][1], 0,0,0);
    if (s + 4 < 36) LDA_S(buf, s + 4);
  }
  #undef LDA_S

  float* dst = sacc + (size_t)ks*KSTR + (size_t)(cid*NB + b)*128*1024;
  #pragma unroll
  for (int mi = 0; mi < 2; ++mi) {
    #pragma unroll
    for (int ni = 0; ni < 2; ++ni) {
      int pxl = R*32 + ni*16 + (lane & 15);
      #pragma unroll
      for (int r = 0; r < 4; ++r) {
        int oc = w*32 + mi*16 + ((lane >> 4) << 2) + r;
        dst[(size_t)oc*1024 + pxl] = acc[mi][ni][r];
      }
    }
  }
}

// ---------------- finalize conv_s: K-sum + bias+ReLU+bf16 pack + borders ---
__global__ __launch_bounds__(256) void k_finS(
    const float* __restrict__ sacc, const float* __restrict__ biasS,
    bf16_t* __restrict__ hP) {
  int x = blockIdx.x;
  int cid = x >> 6, b = (x >> 4) & 3, cb = (x >> 2) & 3, pxq = x & 3;
  int t = threadIdx.x;
  __shared__ float lds[32][260];
  size_t base = (size_t)(cid*NB + b)*128*1024 + (size_t)cb*32*1024 + pxq*256;
  const float* s0 = sacc + base;
  const float* s1 = s0 + KSTR;
  const float* s2 = s1 + KSTR;
  const float* bp = biasS + cid*128 + cb*32;
  #pragma unroll
  for (int it = 0; it < 32; ++it) {
    int i = it*256 + t;
    int och = i >> 8, px = i & 255;
    size_t off = (size_t)och*1024 + px;
    lds[och][px] = fmaxf(s0[off] + s1[off] + s2[off] + bp[och], 0.f);
  }
  __syncthreads();
  size_t plane = (size_t)(cid*NB + b)*4 + cb;
  #pragma unroll
  for (int it = 0; it < 8; ++it) {
    int i2 = it*256 + t;
    int och4 = i2 & 7, px = i2 >> 3;
    int gpx = pxq*256 + px;
    int row = 1 + (gpx >> 5), col = 1 + (gpx & 31);
    s16x4 pk;
    #pragma unroll
    for (int r = 0; r < 4; ++r) pk[r] = (short)f2bf(lds[och4*4 + r][px]);
    *(s16x4*)(hP + (plane*PPX + row*34 + col)*32 + och4*4) = pk;
  }
  for (int i = t; i < 33*32; i += 256) {
    int k = pxq*33 + (i >> 5);
    int ch = i & 31;
    int row, col;
    if (k < 34)      { row = 0;      col = k; }
    else if (k < 68) { row = 33;     col = k - 34; }
    else if (k < 100){ row = k - 67; col = 0; }
    else             { row = k - 99; col = 33; }
    hP[(plane*PPX + row*34 + col)*32 + ch] = 0;
  }
}

// ---------------- conv_g0 + g1 + g2: shared-B LDS, 3-deep A pipeline -------
__global__ __launch_bounds__(256, 4) void k_convG(
    const bf16_t* __restrict__ hP,
    const bf16_t* __restrict__ wpkG0, const bf16_t* __restrict__ wpkG1,
    const bf16_t* __restrict__ wpkG2,
    const float* __restrict__ biasG0, const float* __restrict__ biasG1,
    const float* __restrict__ biasG2,
    bf16_t* __restrict__ gamma0b, float* __restrict__ g1out,
    float* __restrict__ g2out) {
  int z, R, b;
  XCD_DECODE(z, R, b);
  int t = threadIdx.x, lane = t & 63, w = t >> 6;
  const bf16_t* wpk; const float* bias; int obT, cidSel, obSel;
  if (z < 7)       { wpk = wpkG0; bias = biasG0; obT = 104; cidSel = 0; obSel = z*16 + w*4; }
  else if (z == 7) { wpk = wpkG1; bias = biasG1; obT = 4;   cidSel = 1; obSel = 0; }
  else             { wpk = wpkG2; bias = biasG2; obT = 4;   cidSel = 2; obSel = 0; }
  const bf16_t* inRegion = hP + (size_t)((cidSel*NB + b)*4)*(PPX*32);

  __shared__ bf16_t lds[13056];
  STAGE_B(lds, inRegion, R);
  __syncthreads();
  if (z >= 7 && w > 0) return;   // g1/g2: single wave computes

  int koff = lane >> 4;
  int pxc0 = lane & 15, pxc1 = 16 + (lane & 15);
  auto afp = [&](int tp, int jj, int sl) {
    return wpk + ((size_t)(tp*4 + jj)*obT + sl)*512 + lane*8;
  };
  auto blds = [&](int tp, int jj, int pxc) {
    return lds + (((jj*3 + tp/3)*4 + koff)*34 + pxc + tp%3)*8;
  };
  bool act[4];
  #pragma unroll
  for (int mi = 0; mi < 4; ++mi) act[mi] = (obSel + mi) < obT;

  f32x4 acc[4][2];
  #pragma unroll
  for (int mi = 0; mi < 4; ++mi)
    #pragma unroll
    for (int ni = 0; ni < 2; ++ni) acc[mi][ni] = (f32x4){0.f,0.f,0.f,0.f};

  s16x8 A[3][4];
  #define LDA_G(buf, s) do { const int tp=(s)>>2, jj=(s)&3; \
      if (act[0]) A[buf][0]=*(const s16x8*)afp(tp,jj,obSel+0); \
      if (act[1]) A[buf][1]=*(const s16x8*)afp(tp,jj,obSel+1); \
      if (act[2]) A[buf][2]=*(const s16x8*)afp(tp,jj,obSel+2); \
      if (act[3]) A[buf][3]=*(const s16x8*)afp(tp,jj,obSel+3); } while(0)
  LDA_G(0, 0); LDA_G(1, 1); LDA_G(2, 2);
  #pragma unroll
  for (int s = 0; s < 36; ++s) {
    const int tp = s >> 2, jj = s & 3, buf = s % 3;
    s16x8 B0 = *(const s16x8*)blds(tp, jj, pxc0);
    s16x8 B1 = *(const s16x8*)blds(tp, jj, pxc1);
    if (act[0]) { acc[0][0]=__builtin_amdgcn_mfma_f32_16x16x32_bf16(A[buf][0],B0,acc[0][0],0,0,0);
                  acc[0][1]=__builtin_amdgcn_mfma_f32_16x16x32_bf16(A[buf][0],B1,acc[0][1],0,0,0); }
    if (act[1]) { acc[1][0]=__builtin_amdgcn_mfma_f32_16x16x32_bf16(A[buf][1],B0,acc[1][0],0,0,0);
                  acc[1][1]=__builtin_amdgcn_mfma_f32_16x16x32_bf16(A[buf][1],B1,acc[1][1],0,0,0); }
    if (act[2]) { acc[2][0]=__builtin_amdgcn_mfma_f32_16x16x32_bf16(A[buf][2],B0,acc[2][0],0,0,0);
                  acc[2][1]=__builtin_amdgcn_mfma_f32_16x16x32_bf16(A[buf][2],B1,acc[2][1],0,0,0); }
    if (act[3]) { acc[3][0]=__builtin_amdgcn_mfma_f32_16x16x32_bf16(A[buf][3],B0,acc[3][0],0,0,0);
                  acc[3][1]=__builtin_amdgcn_mfma_f32_16x16x32_bf16(A[buf][3],B1,acc[3][1],0,0,0); }
    if (s + 3 < 36) LDA_G(buf, s + 3);
  }
  #undef LDA_G

  #pragma unroll
  for (int mi = 0; mi < 4; ++mi) {
    if (!act[mi]) continue;
    #pragma unroll
    for (int ni = 0; ni < 2; ++ni) {
      int pxl = R*32 + ni*16 + (lane & 15);
      int quad = (lane >> 4) << 2;
      if (z < 7) {
        #pragma unroll
        for (int r = 0; r < 4; ++r) {
          int oc = (obSel + mi)*16 + quad + r;
          if (oc < 1552)
            gamma0b[((size_t)b*1552 + oc)*1024 + pxl] = f2bf(acc[mi][ni][r] + bias[oc]);
        }
      } else if (z == 7) {
        if (mi == 0) {
          #pragma unroll
          for (int r = 0; r < 4; ++r) {
            int oc = quad + r;
            g1out[((size_t)b*16 + oc)*1024 + pxl] = acc[mi][ni][r] + bias[oc];
          }
        }
      } else {
        if (mi < 2) {
          #pragma unroll
          for (int r = 0; r < 4; ++r) {
            int oc = mi*16 + quad + r;
            g2out[((size_t)b*32 + oc)*1024 + pxl] = acc[mi][ni][r] + bias[oc];
          }
        }
      }
    }
  }
}

// ---------------- SPADE0 partial (8 private cg slices) ----------------
__global__ __launch_bounds__(256) void k_epi0p(
    const float* __restrict__ x, const bf16_t* __restrict__ g0,
    const float* __restrict__ w0, const float* __restrict__ lnp,
    float* __restrict__ y0pre) {
  int y = blockIdx.x, b = blockIdx.y, cg = blockIdx.z;
  int t = threadIdx.x, px = t & 31, g8 = t >> 5;
  __shared__ float ps[64], pq[64];
  if (t < 64) { ps[t] = lnp[(b*64 + t)*2]; pq[t] = lnp[(b*64 + t)*2 + 1]; }
  __syncthreads();
  float ssum = 0.f, qsum = 0.f;
  for (int i = 0; i < 64; i++) { ssum += ps[i]; qsum += pq[i]; }
  float mu = ssum * (1.f/LNN);
  float var = qsum * (1.f/LNN) - mu*mu;
  float r = rsqrtf(var + 1e-12f);
  float acc[8];
  #pragma unroll
  for (int o = 0; o < 8; o++) acc[o] = 0.f;
  const float* xb = x + (size_t)b*CM*1024 + y*32 + px;
  const bf16_t* gb = g0 + (size_t)b*1552*1024 + y*32 + px;
  int c0 = cg*192 + g8*24;
  for (int c = c0; c < c0 + 24; c++) {
    float v = (xb[(size_t)c*1024] - mu)*r*(1.f + bf2f(gb[(size_t)c*1024]));
    #pragma unroll
    for (int o = 0; o < 8; o++) acc[o] = fmaf(w0[o*CM + c], v, acc[o]);
  }
  __shared__ float red[8][32][8];
  #pragma unroll
  for (int o = 0; o < 8; o++) red[g8][px][o] = acc[o];
  __syncthreads();
  int o = g8;
  float s = 0.f;
  #pragma unroll
  for (int gg = 0; gg < 8; gg++) s += red[gg][px][o];
  y0pre[((size_t)cg*NB + b)*8192 + o*1024 + y*32 + px] = s;
}

// ---------------- finalize y0 (sum 8 slices + softplus) + LN stats ---------
__global__ __launch_bounds__(256) void k_fin0ln(
    const float* __restrict__ y0pre, const bf16_t* __restrict__ g0,
    const float* __restrict__ bextp, float* __restrict__ y0,
    float* __restrict__ mu_r1) {
  int b = blockIdx.x, t = threadIdx.x;
  __shared__ float bl[256];
  __shared__ float bsum[8];
  bl[t] = bextp[t];
  __syncthreads();
  if (t < 8) {
    float s = 0.f;
    for (int k = 0; k < 32; k++) s += bl[k*8 + t];
    bsum[t] = s;
  }
  __syncthreads();
  float ss = 0.f, qq = 0.f;
  for (int i = t; i < 8192; i += 256) {
    int o = i >> 10, px = i & 1023;
    float s = bsum[o] + bf2f(g0[((size_t)b*1552 + 1536 + o)*1024 + px]);
    #pragma unroll
    for (int k = 0; k < 8; k++) s += y0pre[((size_t)k*NB + b)*8192 + i];
    float v = fmaxf(s, 0.f) + log1pf(expf(-fabsf(s)));
    y0[(size_t)b*8192 + i] = v;
    ss += v; qq = fmaf(v, v, qq);
  }
  __shared__ float rs[256], rq[256];
  rs[t] = ss; rq[t] = qq;
  __syncthreads();
  for (int st = 128; st > 0; st >>= 1) {
    if (t < st) { rs[t] += rs[t+st]; rq[t] += rq[t+st]; }
    __syncthreads();
  }
  if (t == 0) {
    float mu = rs[0]/8192.f, var = rq[0]/8192.f - mu*mu;
    mu_r1[b*2] = mu; mu_r1[b*2+1] = rsqrtf(var + 1e-12f);
  }
}

// ------- SPADE1 epilogue + conv1(1x1,8->16) + softplus + LN partials -------
__global__ __launch_bounds__(256) void k_epi1(
    const float* __restrict__ y0, const float* __restrict__ g1o,
    const float* __restrict__ w1, const float* __restrict__ b1v,
    const float* __restrict__ mu_r, float* __restrict__ y1,
    float* __restrict__ lnp2) {
  int y = blockIdx.x, b = blockIdx.y;
  int t = threadIdx.x, px = t & 31, o = t >> 5;
  float mu = mu_r[b*2], r = mu_r[b*2+1];
  int pg = y*32 + px;
  float gs = g1o[((size_t)b*16 + o)*1024 + pg];
  float bs = g1o[((size_t)b*16 + 8 + o)*1024 + pg];
  float xv = y0[(size_t)b*8192 + o*1024 + pg];
  __shared__ float sl[32][8];
  sl[px][o] = (xv - mu)*r*(1.f + gs) + bs;
  __syncthreads();
  float ss = 0.f, qq = 0.f;
  #pragma unroll
  for (int q = 0; q < 2; q++) {
    int oc = o + q*8;
    float s = b1v[oc];
    #pragma unroll
    for (int c = 0; c < 8; c++) s = fmaf(w1[oc*8 + c], sl[px][c], s);
    float v = fmaxf(s, 0.f) + log1pf(expf(-fabsf(s)));
    y1[(size_t)b*16384 + oc*1024 + pg] = v;
    ss += v; qq = fmaf(v, v, qq);
  }
  __shared__ float rs[256], rq[256];
  rs[t] = ss; rq[t] = qq;
  __syncthreads();
  for (int st = 128; st > 0; st >>= 1) {
    if (t < st) { rs[t] += rs[t+st]; rq[t] += rq[t+st]; }
    __syncthreads();
  }
  if (t == 0) {
    lnp2[(b*32 + y)*2]     = rs[0];
    lnp2[(b*32 + y)*2 + 1] = rq[0];
  }
}

// ------- SPADE2 epilogue + conv2(1x1,16->1) + softplus (LN from partials) --
__global__ __launch_bounds__(256) void k_epi2(
    const float* __restrict__ y1, const float* __restrict__ g2o,
    const float* __restrict__ w2, const float* __restrict__ b2v,
    const float* __restrict__ lnp2, float* __restrict__ out) {
  int y = blockIdx.x, b = blockIdx.y;
  int t = threadIdx.x, px = t & 31, q = t >> 5;
  __shared__ float ps[32], pq[32];
  if (t < 32) { ps[t] = lnp2[(b*32 + t)*2]; pq[t] = lnp2[(b*32 + t)*2 + 1]; }
  __syncthreads();
  float ssum = 0.f, qsum = 0.f;
  #pragma unroll
  for (int i = 0; i < 32; i++) { ssum += ps[i]; qsum += pq[i]; }
  float mu = ssum * (1.f/16384.f);
  float var = qsum * (1.f/16384.f) - mu*mu;
  float r = rsqrtf(var + 1e-12f);
  int pg = y*32 + px;
  __shared__ float sl[32][16];
  #pragma unroll
  for (int qq = 0; qq < 2; qq++) {
    int o = q + qq*8;
    float gs = g2o[((size_t)b*32 + o)*1024 + pg];
    float bs = g2o[((size_t)b*32 + 16 + o)*1024 + pg];
    float xv = y1[(size_t)b*16384 + o*1024 + pg];
    sl[px][o] = (xv - mu)*r*(1.f + gs) + bs;
  }
  __syncthreads();
  if (t < 32) {
    float s = b2v[0];
    #pragma unroll
    for (int c = 0; c < 16; c++) s = fmaf(w2[c], sl[t][c], s);
    out[(size_t)b*1024 + y*32 + t] = fmaxf(s, 0.f) + log1pf(expf(-fabsf(s)));
  }
}

extern "C" void kernel_launch(void* const* d_in, const int* in_sizes, int n_in,
                              void* d_out, int out_size, void* d_ws, size_t ws_size,
                              hipStream_t stream) {
  const float* x_main = (const float*)d_in[0];
  const float* f_sem  = (const float*)d_in[1];
  const int*   seg    = (const int*)d_in[2];
  const float* s0_ws = (const float*)d_in[3];
  const float* s0_bs = (const float*)d_in[4];
  const float* s0_wg = (const float*)d_in[5];
  const float* s0_bg = (const float*)d_in[6];
  const float* s0_wb = (const float*)d_in[7];
  const float* s0_bb = (const float*)d_in[8];
  const float* s1_ws = (const float*)d_in[9];
  const float* s1_bs = (const float*)d_in[10];
  const float* s1_wg = (const float*)d_in[11];
  const float* s1_bg = (const float*)d_in[12];
  const float* s1_wb = (const float*)d_in[13];
  const float* s1_bb = (const float*)d_in[14];
  const float* s2_ws = (const float*)d_in[15];
  const float* s2_bs = (const float*)d_in[16];
  const float* s2_wg = (const float*)d_in[17];
  const float* s2_bg = (const float*)d_in[18];
  const float* s2_wb = (const float*)d_in[19];
  const float* s2_bb = (const float*)d_in[20];
  const float* w0 = (const float*)d_in[21];
  const float* b0 = (const float*)d_in[22];
  const float* w1 = (const float*)d_in[23];
  const float* b1 = (const float*)d_in[24];
  const float* w2 = (const float*)d_in[25];
  const float* b2 = (const float*)d_in[26];

  float* ws = (float*)d_ws;
  size_t o = 0;
  float* lnp   = ws + o; o += 512;                 // [4b][64][2] LN0 partials
  float* lnp2  = ws + o; o += 256;                 // [4b][32][2] LN2 partials
  float* y0pre = ws + o; o += 262144;              // [8cg][4b][8192]
  float* wbfp  = ws + o; o += 294912;              // [32ks][8][1152]
  float* bextp = ws + o; o += 256;                 // [32ks][8]
  bf16_t* hP   = (bf16_t*)(ws + o); o += 887808;   // 1,775,616 bf16
  float* sacc  = ws + o;                            // [3ks][3cid][4b][128][1024] fp32
  bf16_t* gamma0b = (bf16_t*)sacc;                  // aliases sacc (dead before convG)
  o += 4718592;
  float* sums   = ws + o; o += 98304;
  float* cnt    = ws + o; o += 256;
  bf16_t* smP   = (bf16_t*)(ws + o); o += 887808;  // 1,775,616 bf16
  bf16_t* wpkS  = (bf16_t*)(ws + o); o += 663552;  // 1,327,104 bf16
  bf16_t* wpkG0 = (bf16_t*)(ws + o); o += 958464;  // 1,916,928 bf16
  bf16_t* wpkG1 = (bf16_t*)(ws + o); o += 36864;
  bf16_t* wpkG2 = (bf16_t*)(ws + o); o += 36864;
  float* biasS  = ws + o; o += 384;
  float* biasG0 = ws + o; o += 1664;
  float* biasG1 = ws + o; o += 16;
  float* biasG2 = ws + o; o += 32;
  float* mu_r1  = ws + o; o += 8;
  float* y0     = ws + o; o += 32768;
  float* y1     = ws + o; o += 65536;
  float* g1out  = ws + o; o += 65536;
  float* g2out  = ws + o; o += 131072;

  hipLaunchKernelGGL(k_front, dim3(2016), dim3(256), 0, stream,
                     f_sem, seg, sums, cnt,
                     w0, s0_wb, s0_bb, b0,
                     s0_bs, s1_bs, s2_bs, s0_bg, s1_bg, s1_bb, s2_bg, s2_bb,
                     wbfp, bextp, biasS, biasG0, biasG1, biasG2,
                     x_main, lnp);
  hipLaunchKernelGGL(k_mid, dim3(5752), dim3(256), 0, stream,
                     sums, cnt, seg, smP,
                     s0_ws, s1_ws, s2_ws, s0_wg, wbfp, s1_wg, s1_wb, s2_wg, s2_wb,
                     wpkS, wpkG0, wpkG1, wpkG2);
  hipLaunchKernelGGL(k_convS, dim3(1152), dim3(256), 0, stream, smP, wpkS, sacc);
  hipLaunchKernelGGL(k_finS, dim3(192), dim3(256), 0, stream, sacc, biasS, hP);
  hipLaunchKernelGGL(k_convG, dim3(1152), dim3(256), 0, stream,
                     hP, wpkG0, wpkG1, wpkG2, biasG0, biasG1, biasG2,
                     gamma0b, g1out, g2out);
  hipLaunchKernelGGL(k_epi0p, dim3(32, NB, 8), dim3(256), 0, stream,
                     x_main, gamma0b, w0, lnp, y0pre);
  hipLaunchKernelGGL(k_fin0ln, dim3(NB), dim3(256), 0, stream, y0pre, gamma0b, bextp, y0, mu_r1);
  hipLaunchKernelGGL(k_epi1, dim3(32, NB), dim3(256), 0, stream, y0, g1out, w1, b1, mu_r1, y1, lnp2);
  hipLaunchKernelGGL(k_epi2, dim3(32, NB), dim3(256), 0, stream, y1, g2out, w2, b2, lnp2, (float*)d_out);
}

// Round 16
// 164.613 us; speedup vs baseline: 1.2283x; 1.2283x over previous
//
#include <hip/hip_runtime.h>
#include <math.h>

#define NB 4
#define CD 384
#define CM 1536
#define HIDC 128
#define HRES 448
#define NSEG 64
#define LNN (CM*1024)
#define PPX 1156                 // 34*34 padded plane
#define KSTR ((size_t)3*NB*128*1024)   // sacc per-ksplit stride

typedef unsigned short bf16_t;
typedef __attribute__((ext_vector_type(8))) short s16x8;
typedef __attribute__((ext_vector_type(4))) short s16x4;
typedef __attribute__((ext_vector_type(4))) float f32x4;

__device__ inline bf16_t f2bf(float v) {
  unsigned int x = __float_as_uint(v);
  unsigned int r = (x + 0x7fffu + ((x >> 16) & 1u)) >> 16;  // RNE, finite
  return (bf16_t)r;
}
__device__ inline float bf2f(bf16_t u) {
  return __uint_as_float(((unsigned int)u) << 16);
}

// ================= merged front: seg | fold3b | ln0 ========================
__device__ void seg_body(int c, int b, int t,
                         const float* __restrict__ fsem, const int* __restrict__ seg,
                         float* __restrict__ sums, float* __restrict__ cnt) {
  __shared__ float ssum[NSEG];
  __shared__ float scnt[NSEG];
  if (t < NSEG) { ssum[t] = 0.f; scnt[t] = 0.f; }
  __syncthreads();
  const float* f = fsem + ((size_t)b*CD + c)*1024;
  const int* sg = seg + (size_t)b*HRES*HRES;
  #pragma unroll
  for (int i = 0; i < 4; i++) {
    int p = i*256 + t;
    int py = p >> 5, px = p & 31;
    int id = sg[14*py*HRES + 14*px];
    id = min(max(id, 0), NSEG-1);
    atomicAdd(&ssum[id], f[p]);
    if (c == 0) atomicAdd(&scnt[id], 1.f);
  }
  __syncthreads();
  if (t < NSEG) {
    sums[((size_t)b*NSEG + t)*CD + c] = ssum[t];
    if (c == 0) cnt[b*NSEG + t] = scnt[t];
  }
}

__device__ void fold3b_body(int bx, int ks, int t,
                            const float* __restrict__ w0, const float* __restrict__ wb,
                            const float* __restrict__ bb, const float* __restrict__ b0v,
                            const float* s0bs, const float* s1bs, const float* s2bs,
                            const float* s0bg, const float* s1bg, const float* s1bb,
                            const float* s2bg, const float* s2bb,
                            float* __restrict__ wbfp, float* __restrict__ bextp,
                            float* biasS, float* biasG0, float* biasG1, float* biasG2) {
  if (bx == 6) {
    if (ks != 0) return;
    for (int i = t; i < 128; i += 256) {
      biasS[i] = s0bs[i]; biasS[128+i] = s1bs[i]; biasS[256+i] = s2bs[i];
    }
    for (int i = t; i < 1664; i += 256) biasG0[i] = (i < 1536) ? s0bg[i] : 0.f;
    if (t < 16) biasG1[t] = (t < 8) ? s1bg[t] : s1bb[t-8];
    if (t < 32) biasG2[t] = (t < 16) ? s2bg[t] : s2bb[t-16];
    return;
  }
  int c0 = ks*48;
  if (bx < 5) {
    int jk = bx*256 + t;
    if (jk >= 1152) return;
    float acc[8];
    #pragma unroll
    for (int o = 0; o < 8; o++) acc[o] = 0.f;
    for (int c = c0; c < c0 + 48; c++) {
      float wv = wb[(size_t)c*1152 + jk];
      #pragma unroll
      for (int o = 0; o < 8; o++) acc[o] = fmaf(w0[o*CM + c], wv, acc[o]);
    }
    #pragma unroll
    for (int o = 0; o < 8; o++) wbfp[((size_t)ks*8 + o)*1152 + jk] = acc[o];
  } else {
    if (t < 8) {
      float s = (ks == 0) ? b0v[t] : 0.f;
      for (int c = c0; c < c0 + 48; c++) s = fmaf(w0[t*CM + c], bb[c], s);
      bextp[ks*8 + t] = s;
    }
  }
}

__device__ void ln0_body(int cx, int b, int t,
                         const float* __restrict__ x, float* __restrict__ lnp) {
  const int CHUNK = LNN/64;
  const f32x4* xb = (const f32x4*)(x + (size_t)b*LNN + (size_t)cx*CHUNK);
  float s = 0.f, q = 0.f;
  for (int i = t; i < CHUNK/4; i += 256) {
    f32x4 v = xb[i];
    s += v[0] + v[1] + v[2] + v[3];
    q = fmaf(v[0],v[0], fmaf(v[1],v[1], fmaf(v[2],v[2], fmaf(v[3],v[3], q))));
  }
  __shared__ float rs[256], rq[256];
  rs[t] = s; rq[t] = q;
  __syncthreads();
  for (int st = 128; st > 0; st >>= 1) {
    if (t < st) { rs[t] += rs[t+st]; rq[t] += rq[t+st]; }
    __syncthreads();
  }
  if (t == 0) {
    lnp[(b*64 + cx)*2]     = rs[0];
    lnp[(b*64 + cx)*2 + 1] = rq[0];
  }
}

__global__ __launch_bounds__(256) void k_front(
    const float* fsem, const int* seg, float* sums, float* cnt,
    const float* w0, const float* wb, const float* bb, const float* b0v,
    const float* s0bs, const float* s1bs, const float* s2bs,
    const float* s0bg, const float* s1bg, const float* s1bb,
    const float* s2bg, const float* s2bb,
    float* wbfp, float* bextp,
    float* biasS, float* biasG0, float* biasG1, float* biasG2,
    const float* x, float* lnp) {
  int L = blockIdx.x, t = threadIdx.x;
  if (L < 1536) {
    seg_body(L % 384, L / 384, t, fsem, seg, sums, cnt);
  } else if (L < 1760) {
    int i2 = L - 1536;
    fold3b_body(i2 % 7, i2 / 7, t, w0, wb, bb, b0v,
                s0bs, s1bs, s2bs, s0bg, s1bg, s1bb, s2bg, s2bb,
                wbfp, bextp, biasS, biasG0, biasG1, biasG2);
  } else {
    int i3 = L - 1760;
    ln0_body(i3 & 63, i3 >> 6, t, x, lnp);
  }
}

// ================= merged mid: paint | packall =============================
__device__ void paint_body(int oyp, int b, int t,
                           const float* __restrict__ sums, const float* __restrict__ cnt,
                           const int* __restrict__ seg, bf16_t* __restrict__ smP) {
  __shared__ int sid[32][4];
  __shared__ float sinv[32][4];
  bool border_row = (oyp == 0 || oyp == 33);
  if (!border_row && t < 32) {
    int oy = oyp - 1;
    const int* sg = seg + (size_t)b*HRES*HRES;
    int y0 = 14*oy + 6, x0 = 14*t + 6;
    int ids[4];
    ids[0] = sg[y0*HRES + x0];     ids[1] = sg[y0*HRES + x0 + 1];
    ids[2] = sg[(y0+1)*HRES + x0]; ids[3] = sg[(y0+1)*HRES + x0 + 1];
    #pragma unroll
    for (int k = 0; k < 4; k++) {
      int id = min(max(ids[k], 0), NSEG-1);
      sid[t][k] = id;
      float c = cnt[b*NSEG + id];
      sinv[t][k] = (c > 0.f) ? 1.f/c : 0.f;
    }
  }
  __syncthreads();
  const float* sb = sums + (size_t)b*NSEG*CD;
  for (int i = t; i < 34*CD; i += 256) {
    int c = i % CD;
    int xp = i / CD;
    float v = 0.f;
    if (!border_row && xp != 0 && xp != 33) {
      int ox = xp - 1;
      v = 0.25f*(sinv[ox][0]*sb[sid[ox][0]*CD + c] + sinv[ox][1]*sb[sid[ox][1]*CD + c]
               + sinv[ox][2]*sb[sid[ox][2]*CD + c] + sinv[ox][3]*sb[sid[ox][3]*CD + c]);
    }
    smP[(((size_t)b*12 + (c>>5))*PPX + oyp*34 + xp)*32 + (c&31)] = f2bf(v);
  }
}

__device__ void packall_body(int bx, int cfg, int t,
    const float* s0_ws, const float* s1_ws, const float* s2_ws,
    const float* s0_wg, const float* wbfp,
    const float* s1_wg, const float* s1_wb,
    const float* s2_wg, const float* s2_wb,
    bf16_t* wpkS, bf16_t* wpkG0, bf16_t* wpkG1, bf16_t* wpkG2) {
  const float* wA; const float* wB; int OA, OBn, I, obT, CBn; bf16_t* dst;
  switch (cfg) {
    case 0: wA=s0_ws; wB=nullptr; OA=128;  OBn=0;  I=384; obT=8;   CBn=12; dst=wpkS;          break;
    case 1: wA=s1_ws; wB=nullptr; OA=128;  OBn=0;  I=384; obT=8;   CBn=12; dst=wpkS+442368;   break;
    case 2: wA=s2_ws; wB=nullptr; OA=128;  OBn=0;  I=384; obT=8;   CBn=12; dst=wpkS+884736;   break;
    case 3: wA=s0_wg; wB=wbfp;    OA=1536; OBn=8;  I=128; obT=104; CBn=4;  dst=wpkG0;         break;
    case 4: wA=s1_wg; wB=s1_wb;   OA=8;    OBn=8;  I=128; obT=4;   CBn=4;  dst=wpkG1;         break;
    default:wA=s2_wg; wB=s2_wb;   OA=16;   OBn=16; I=128; obT=4;   CBn=4;  dst=wpkG2;         break;
  }
  size_t idx = (size_t)bx*256 + t;
  size_t tot = (size_t)9*CBn*obT*64;
  if (idx >= tot) return;
  int lane = idx & 63;
  size_t q = idx >> 6;
  int ob = q % obT; q /= obT;
  int cb = q % CBn;
  int tap = q / CBn;
  int o = ob*16 + (lane & 15);
  int ib = cb*32 + ((lane >> 4) << 3);
  s16x8 vv;
  #pragma unroll
  for (int j = 0; j < 8; j++) {
    int i = ib + j;
    float v = 0.f;
    if (o < OA) v = wA[((size_t)o*I + i)*9 + tap];
    else if (o - OA < OBn) {
      if (cfg == 3) {
        float s = 0.f;
        for (int ks = 0; ks < 32; ks++)
          s += wB[((size_t)ks*8 + (o - OA))*1152 + i*9 + tap];
        v = s;
      } else {
        v = wB[((size_t)(o-OA)*I + i)*9 + tap];
      }
    }
    vv[j] = (short)f2bf(v);
  }
  *(s16x8*)(dst + idx*8) = vv;
}

__global__ __launch_bounds__(256) void k_mid(
    const float* sums, const float* cnt, const int* seg, bf16_t* smP,
    const float* s0_ws, const float* s1_ws, const float* s2_ws,
    const float* s0_wg, const float* wbfp,
    const float* s1_wg, const float* s1_wb,
    const float* s2_wg, const float* s2_wb,
    bf16_t* wpkS, bf16_t* wpkG0, bf16_t* wpkG1, bf16_t* wpkG2) {
  int L = blockIdx.x, t = threadIdx.x;
  if (L < 136) {
    paint_body(L % 34, L / 34, t, sums, cnt, seg, smP);
  } else {
    int i2 = L - 136;
    packall_body(i2 % 936, i2 / 936, t,
                 s0_ws, s1_ws, s2_ws, s0_wg, wbfp, s1_wg, s1_wb, s2_wg, s2_wb,
                 wpkS, wpkG0, wpkG1, wpkG2);
  }
}

// ---- shared-B LDS staging: layout [cb][row3][koff4][px34][8 bf16] ---------
#define STAGE_B(ldsbuf, inRegion, R) do { \
    for (int i = t; i < 1632; i += 256) { \
      int c_ = i & 3; \
      int q_ = i >> 2; \
      int px_ = q_ % 34; \
      int r2_ = q_ / 34; \
      int row_ = r2_ % 3; \
      int cb_ = r2_ / 3; \
      *(s16x8*)(ldsbuf + (((cb_*3 + row_)*4 + c_)*34 + px_)*8) = \
        *(const s16x8*)((inRegion) + ((size_t)cb_*PPX + ((R) + row_)*34 + px_)*32 + c_*8); \
    } \
  } while (0)

// XCD z-colocation decode: blocks with same z share (blockIdx % 8) -> one XCD L2
#define XCD_DECODE(z, R, b) do { \
    int L_ = blockIdx.x; \
    if (L_ < 1024) { z = L_ & 7; int j_ = L_ >> 3; R = j_ & 31; b = j_ >> 5; } \
    else { int j_ = L_ - 1024; z = 8; R = j_ & 31; b = j_ >> 5; } \
  } while (0)

// ---------------- conv_s: K-split x3, shared-B LDS, 2-deep ping-pong -------
__global__ __launch_bounds__(256, 4) void k_convS(
    const bf16_t* __restrict__ smP, const bf16_t* __restrict__ wpkS,
    float* __restrict__ sacc) {
  int z, R, b;
  XCD_DECODE(z, R, b);
  int cid = z/3, ks = z - cid*3;
  int t = threadIdx.x, lane = t & 63, w = t >> 6;
  int cb0 = ks*4;
  const bf16_t* wpk = wpkS + (size_t)cid*442368;
  const bf16_t* inRegion = smP + ((size_t)b*12 + cb0)*(PPX*32);

  __shared__ bf16_t lds[13056];
  STAGE_B(lds, inRegion, R);
  __syncthreads();

  int koff = lane >> 4;
  int pxc0 = lane & 15, pxc1 = 16 + (lane & 15);
  auto afp = [&](int tp, int jj, int mi) {
    return wpk + (size_t)((tp*12 + cb0 + jj)*8 + w*2 + mi)*512 + lane*8;
  };
  auto blds = [&](int tp, int jj, int pxc) {
    return lds + (((jj*3 + tp/3)*4 + koff)*34 + pxc + tp%3)*8;
  };
  f32x4 acc[2][2];
  #pragma unroll
  for (int mi = 0; mi < 2; ++mi)
    #pragma unroll
    for (int ni = 0; ni < 2; ++ni) acc[mi][ni] = (f32x4){0.f,0.f,0.f,0.f};

  s16x8 A0[2], A1[2];
  #define LDA_S(A, s) do { const int tp=(s)>>2, jj=(s)&3; \
      A[0]=*(const s16x8*)afp(tp,jj,0); A[1]=*(const s16x8*)afp(tp,jj,1); } while(0)
  LDA_S(A0, 0); LDA_S(A1, 1);
  #pragma unroll
  for (int s = 0; s < 36; ++s) {
    const int tp = s >> 2, jj = s & 3;
    s16x8 B0 = *(const s16x8*)blds(tp, jj, pxc0);
    s16x8 B1 = *(const s16x8*)blds(tp, jj, pxc1);
    if (s & 1) {
      acc[0][0] = __builtin_amdgcn_mfma_f32_16x16x32_bf16(A1[0], B0, acc[0][0], 0,0,0);
      acc[0][1] = __builtin_amdgcn_mfma_f32_16x16x32_bf16(A1[0], B1, acc[0][1], 0,0,0);
      acc[1][0] = __builtin_amdgcn_mfma_f32_16x16x32_bf16(A1[1], B0, acc[1][0], 0,0,0);
      acc[1][1] = __builtin_amdgcn_mfma_f32_16x16x32_bf16(A1[1], B1, acc[1][1], 0,0,0);
      if (s + 2 < 36) LDA_S(A1, s + 2);
    } else {
      acc[0][0] = __builtin_amdgcn_mfma_f32_16x16x32_bf16(A0[0], B0, acc[0][0], 0,0,0);
      acc[0][1] = __builtin_amdgcn_mfma_f32_16x16x32_bf16(A0[0], B1, acc[0][1], 0,0,0);
      acc[1][0] = __builtin_amdgcn_mfma_f32_16x16x32_bf16(A0[1], B0, acc[1][0], 0,0,0);
      acc[1][1] = __builtin_amdgcn_mfma_f32_16x16x32_bf16(A0[1], B1, acc[1][1], 0,0,0);
      if (s + 2 < 36) LDA_S(A0, s + 2);
    }
  }
  #undef LDA_S

  float* dst = sacc + (size_t)ks*KSTR + (size_t)(cid*NB + b)*128*1024;
  #pragma unroll
  for (int mi = 0; mi < 2; ++mi) {
    #pragma unroll
    for (int ni = 0; ni < 2; ++ni) {
      int pxl = R*32 + ni*16 + (lane & 15);
      #pragma unroll
      for (int r = 0; r < 4; ++r) {
        int oc = w*32 + mi*16 + ((lane >> 4) << 2) + r;
        dst[(size_t)oc*1024 + pxl] = acc[mi][ni][r];
      }
    }
  }
}

// ---------------- finalize conv_s: K-sum + bias+ReLU+bf16 pack + borders ---
__global__ __launch_bounds__(256) void k_finS(
    const float* __restrict__ sacc, const float* __restrict__ biasS,
    bf16_t* __restrict__ hP) {
  int x = blockIdx.x;
  int cid = x >> 6, b = (x >> 4) & 3, cb = (x >> 2) & 3, pxq = x & 3;
  int t = threadIdx.x;
  __shared__ float lds[32][260];
  size_t base = (size_t)(cid*NB + b)*128*1024 + (size_t)cb*32*1024 + pxq*256;
  const float* s0 = sacc + base;
  const float* s1 = s0 + KSTR;
  const float* s2 = s1 + KSTR;
  const float* bp = biasS + cid*128 + cb*32;
  #pragma unroll
  for (int it = 0; it < 32; ++it) {
    int i = it*256 + t;
    int och = i >> 8, px = i & 255;
    size_t off = (size_t)och*1024 + px;
    lds[och][px] = fmaxf(s0[off] + s1[off] + s2[off] + bp[och], 0.f);
  }
  __syncthreads();
  size_t plane = (size_t)(cid*NB + b)*4 + cb;
  #pragma unroll
  for (int it = 0; it < 8; ++it) {
    int i2 = it*256 + t;
    int och4 = i2 & 7, px = i2 >> 3;
    int gpx = pxq*256 + px;
    int row = 1 + (gpx >> 5), col = 1 + (gpx & 31);
    s16x4 pk;
    #pragma unroll
    for (int r = 0; r < 4; ++r) pk[r] = (short)f2bf(lds[och4*4 + r][px]);
    *(s16x4*)(hP + (plane*PPX + row*34 + col)*32 + och4*4) = pk;
  }
  for (int i = t; i < 33*32; i += 256) {
    int k = pxq*33 + (i >> 5);
    int ch = i & 31;
    int row, col;
    if (k < 34)      { row = 0;      col = k; }
    else if (k < 68) { row = 33;     col = k - 34; }
    else if (k < 100){ row = k - 67; col = 0; }
    else             { row = k - 99; col = 33; }
    hP[(plane*PPX + row*34 + col)*32 + ch] = 0;
  }
}

// ---------------- conv_g0 + g1 + g2: shared-B LDS, 2-deep ping-pong --------
__global__ __launch_bounds__(256, 4) void k_convG(
    const bf16_t* __restrict__ hP,
    const bf16_t* __restrict__ wpkG0, const bf16_t* __restrict__ wpkG1,
    const bf16_t* __restrict__ wpkG2,
    const float* __restrict__ biasG0, const float* __restrict__ biasG1,
    const float* __restrict__ biasG2,
    bf16_t* __restrict__ gamma0b, float* __restrict__ g1out,
    float* __restrict__ g2out) {
  int z, R, b;
  XCD_DECODE(z, R, b);
  int t = threadIdx.x, lane = t & 63, w = t >> 6;
  const bf16_t* wpk; const float* bias; int obT, cidSel, obSel;
  if (z < 7)       { wpk = wpkG0; bias = biasG0; obT = 104; cidSel = 0; obSel = z*16 + w*4; }
  else if (z == 7) { wpk = wpkG1; bias = biasG1; obT = 4;   cidSel = 1; obSel = 0; }
  else             { wpk = wpkG2; bias = biasG2; obT = 4;   cidSel = 2; obSel = 0; }
  const bf16_t* inRegion = hP + (size_t)((cidSel*NB + b)*4)*(PPX*32);

  __shared__ bf16_t lds[13056];
  STAGE_B(lds, inRegion, R);
  __syncthreads();
  if (z >= 7 && w > 0) return;   // g1/g2: single wave computes

  int koff = lane >> 4;
  int pxc0 = lane & 15, pxc1 = 16 + (lane & 15);
  auto afp = [&](int tp, int jj, int sl) {
    return wpk + ((size_t)(tp*4 + jj)*obT + sl)*512 + lane*8;
  };
  auto blds = [&](int tp, int jj, int pxc) {
    return lds + (((jj*3 + tp/3)*4 + koff)*34 + pxc + tp%3)*8;
  };
  bool act[4];
  #pragma unroll
  for (int mi = 0; mi < 4; ++mi) act[mi] = (obSel + mi) < obT;

  f32x4 acc[4][2];
  #pragma unroll
  for (int mi = 0; mi < 4; ++mi)
    #pragma unroll
    for (int ni = 0; ni < 2; ++ni) acc[mi][ni] = (f32x4){0.f,0.f,0.f,0.f};

  s16x8 A0[4], A1[4];
  #define LDA_G(A, s) do { const int tp=(s)>>2, jj=(s)&3; \
      if (act[0]) A[0]=*(const s16x8*)afp(tp,jj,obSel+0); \
      if (act[1]) A[1]=*(const s16x8*)afp(tp,jj,obSel+1); \
      if (act[2]) A[2]=*(const s16x8*)afp(tp,jj,obSel+2); \
      if (act[3]) A[3]=*(const s16x8*)afp(tp,jj,obSel+3); } while(0)
  #define MMA_G(A, B0, B1) do { \
      if (act[0]) { acc[0][0]=__builtin_amdgcn_mfma_f32_16x16x32_bf16(A[0],B0,acc[0][0],0,0,0); \
                    acc[0][1]=__builtin_amdgcn_mfma_f32_16x16x32_bf16(A[0],B1,acc[0][1],0,0,0); } \
      if (act[1]) { acc[1][0]=__builtin_amdgcn_mfma_f32_16x16x32_bf16(A[1],B0,acc[1][0],0,0,0); \
                    acc[1][1]=__builtin_amdgcn_mfma_f32_16x16x32_bf16(A[1],B1,acc[1][1],0,0,0); } \
      if (act[2]) { acc[2][0]=__builtin_amdgcn_mfma_f32_16x16x32_bf16(A[2],B0,acc[2][0],0,0,0); \
                    acc[2][1]=__builtin_amdgcn_mfma_f32_16x16x32_bf16(A[2],B1,acc[2][1],0,0,0); } \
      if (act[3]) { acc[3][0]=__builtin_amdgcn_mfma_f32_16x16x32_bf16(A[3],B0,acc[3][0],0,0,0); \
                    acc[3][1]=__builtin_amdgcn_mfma_f32_16x16x32_bf16(A[3],B1,acc[3][1],0,0,0); } \
  } while (0)
  LDA_G(A0, 0); LDA_G(A1, 1);
  #pragma unroll
  for (int s = 0; s < 36; ++s) {
    const int tp = s >> 2, jj = s & 3;
    s16x8 B0 = *(const s16x8*)blds(tp, jj, pxc0);
    s16x8 B1 = *(const s16x8*)blds(tp, jj, pxc1);
    if (s & 1) {
      MMA_G(A1, B0, B1);
      if (s + 2 < 36) LDA_G(A1, s + 2);
    } else {
      MMA_G(A0, B0, B1);
      if (s + 2 < 36) LDA_G(A0, s + 2);
    }
  }
  #undef LDA_G
  #undef MMA_G

  #pragma unroll
  for (int mi = 0; mi < 4; ++mi) {
    if (!act[mi]) continue;
    #pragma unroll
    for (int ni = 0; ni < 2; ++ni) {
      int pxl = R*32 + ni*16 + (lane & 15);
      int quad = (lane >> 4) << 2;
      if (z < 7) {
        #pragma unroll
        for (int r = 0; r < 4; ++r) {
          int oc = (obSel + mi)*16 + quad + r;
          if (oc < 1552)
            gamma0b[((size_t)b*1552 + oc)*1024 + pxl] = f2bf(acc[mi][ni][r] + bias[oc]);
        }
      } else if (z == 7) {
        if (mi == 0) {
          #pragma unroll
          for (int r = 0; r < 4; ++r) {
            int oc = quad + r;
            g1out[((size_t)b*16 + oc)*1024 + pxl] = acc[mi][ni][r] + bias[oc];
          }
        }
      } else {
        if (mi < 2) {
          #pragma unroll
          for (int r = 0; r < 4; ++r) {
            int oc = mi*16 + quad + r;
            g2out[((size_t)b*32 + oc)*1024 + pxl] = acc[mi][ni][r] + bias[oc];
          }
        }
      }
    }
  }
}

// ---------------- SPADE0 partial (8 private cg slices) ----------------
__global__ __launch_bounds__(256) void k_epi0p(
    const float* __restrict__ x, const bf16_t* __restrict__ g0,
    const float* __restrict__ w0, const float* __restrict__ lnp,
    float* __restrict__ y0pre) {
  int y = blockIdx.x, b = blockIdx.y, cg = blockIdx.z;
  int t = threadIdx.x, px = t & 31, g8 = t >> 5;
  __shared__ float ps[64], pq[64];
  if (t < 64) { ps[t] = lnp[(b*64 + t)*2]; pq[t] = lnp[(b*64 + t)*2 + 1]; }
  __syncthreads();
  float ssum = 0.f, qsum = 0.f;
  for (int i = 0; i < 64; i++) { ssum += ps[i]; qsum += pq[i]; }
  float mu = ssum * (1.f/LNN);
  float var = qsum * (1.f/LNN) - mu*mu;
  float r = rsqrtf(var + 1e-12f);
  float acc[8];
  #pragma unroll
  for (int o = 0; o < 8; o++) acc[o] = 0.f;
  const float* xb = x + (size_t)b*CM*1024 + y*32 + px;
  const bf16_t* gb = g0 + (size_t)b*1552*1024 + y*32 + px;
  int c0 = cg*192 + g8*24;
  for (int c = c0; c < c0 + 24; c++) {
    float v = (xb[(size_t)c*1024] - mu)*r*(1.f + bf2f(gb[(size_t)c*1024]));
    #pragma unroll
    for (int o = 0; o < 8; o++) acc[o] = fmaf(w0[o*CM + c], v, acc[o]);
  }
  __shared__ float red[8][32][8];
  #pragma unroll
  for (int o = 0; o < 8; o++) red[g8][px][o] = acc[o];
  __syncthreads();
  int o = g8;
  float s = 0.f;
  #pragma unroll
  for (int gg = 0; gg < 8; gg++) s += red[gg][px][o];
  y0pre[((size_t)cg*NB + b)*8192 + o*1024 + y*32 + px] = s;
}

// ---------------- finalize y0 (sum 8 slices + softplus) + LN stats ---------
__global__ __launch_bounds__(256) void k_fin0ln(
    const float* __restrict__ y0pre, const bf16_t* __restrict__ g0,
    const float* __restrict__ bextp, float* __restrict__ y0,
    float* __restrict__ mu_r1) {
  int b = blockIdx.x, t = threadIdx.x;
  __shared__ float bl[256];
  __shared__ float bsum[8];
  bl[t] = bextp[t];
  __syncthreads();
  if (t < 8) {
    float s = 0.f;
    for (int k = 0; k < 32; k++) s += bl[k*8 + t];
    bsum[t] = s;
  }
  __syncthreads();
  float ss = 0.f, qq = 0.f;
  for (int i = t; i < 8192; i += 256) {
    int o = i >> 10, px = i & 1023;
    float s = bsum[o] + bf2f(g0[((size_t)b*1552 + 1536 + o)*1024 + px]);
    #pragma unroll
    for (int k = 0; k < 8; k++) s += y0pre[((size_t)k*NB + b)*8192 + i];
    float v = fmaxf(s, 0.f) + log1pf(expf(-fabsf(s)));
    y0[(size_t)b*8192 + i] = v;
    ss += v; qq = fmaf(v, v, qq);
  }
  __shared__ float rs[256], rq[256];
  rs[t] = ss; rq[t] = qq;
  __syncthreads();
  for (int st = 128; st > 0; st >>= 1) {
    if (t < st) { rs[t] += rs[t+st]; rq[t] += rq[t+st]; }
    __syncthreads();
  }
  if (t == 0) {
    float mu = rs[0]/8192.f, var = rq[0]/8192.f - mu*mu;
    mu_r1[b*2] = mu; mu_r1[b*2+1] = rsqrtf(var + 1e-12f);
  }
}

// ------- SPADE1 epilogue + conv1(1x1,8->16) + softplus + LN partials -------
__global__ __launch_bounds__(256) void k_epi1(
    const float* __restrict__ y0, const float* __restrict__ g1o,
    const float* __restrict__ w1, const float* __restrict__ b1v,
    const float* __restrict__ mu_r, float* __restrict__ y1,
    float* __restrict__ lnp2) {
  int y = blockIdx.x, b = blockIdx.y;
  int t = threadIdx.x, px = t & 31, o = t >> 5;
  float mu = mu_r[b*2], r = mu_r[b*2+1];
  int pg = y*32 + px;
  float gs = g1o[((size_t)b*16 + o)*1024 + pg];
  float bs = g1o[((size_t)b*16 + 8 + o)*1024 + pg];
  float xv = y0[(size_t)b*8192 + o*1024 + pg];
  __shared__ float sl[32][8];
  sl[px][o] = (xv - mu)*r*(1.f + gs) + bs;
  __syncthreads();
  float ss = 0.f, qq = 0.f;
  #pragma unroll
  for (int q = 0; q < 2; q++) {
    int oc = o + q*8;
    float s = b1v[oc];
    #pragma unroll
    for (int c = 0; c < 8; c++) s = fmaf(w1[oc*8 + c], sl[px][c], s);
    float v = fmaxf(s, 0.f) + log1pf(expf(-fabsf(s)));
    y1[(size_t)b*16384 + oc*1024 + pg] = v;
    ss += v; qq = fmaf(v, v, qq);
  }
  __shared__ float rs[256], rq[256];
  rs[t] = ss; rq[t] = qq;
  __syncthreads();
  for (int st = 128; st > 0; st >>= 1) {
    if (t < st) { rs[t] += rs[t+st]; rq[t] += rq[t+st]; }
    __syncthreads();
  }
  if (t == 0) {
    lnp2[(b*32 + y)*2]     = rs[0];
    lnp2[(b*32 + y)*2 + 1] = rq[0];
  }
}

// ------- SPADE2 epilogue + conv2(1x1,16->1) + softplus (LN from partials) --
__global__ __launch_bounds__(256) void k_epi2(
    const float* __restrict__ y1, const float* __restrict__ g2o,
    const float* __restrict__ w2, const float* __restrict__ b2v,
    const float* __restrict__ lnp2, float* __restrict__ out) {
  int y = blockIdx.x, b = blockIdx.y;
  int t = threadIdx.x, px = t & 31, q = t >> 5;
  __shared__ float ps[32], pq[32];
  if (t < 32) { ps[t] = lnp2[(b*32 + t)*2]; pq[t] = lnp2[(b*32 + t)*2 + 1]; }
  __syncthreads();
  float ssum = 0.f, qsum = 0.f;
  #pragma unroll
  for (int i = 0; i < 32; i++) { ssum += ps[i]; qsum += pq[i]; }
  float mu = ssum * (1.f/16384.f);
  float var = qsum * (1.f/16384.f) - mu*mu;
  float r = rsqrtf(var + 1e-12f);
  int pg = y*32 + px;
  __shared__ float sl[32][16];
  #pragma unroll
  for (int qq = 0; qq < 2; qq++) {
    int o = q + qq*8;
    float gs = g2o[((size_t)b*32 + o)*1024 + pg];
    float bs = g2o[((size_t)b*32 + 16 + o)*1024 + pg];
    float xv = y1[(size_t)b*16384 + o*1024 + pg];
    sl[px][o] = (xv - mu)*r*(1.f + gs) + bs;
  }
  __syncthreads();
  if (t < 32) {
    float s = b2v[0];
    #pragma unroll
    for (int c = 0; c < 16; c++) s = fmaf(w2[c], sl[t][c], s);
    out[(size_t)b*1024 + y*32 + t] = fmaxf(s, 0.f) + log1pf(expf(-fabsf(s)));
  }
}

extern "C" void kernel_launch(void* const* d_in, const int* in_sizes, int n_in,
                              void* d_out, int out_size, void* d_ws, size_t ws_size,
                              hipStream_t stream) {
  const float* x_main = (const float*)d_in[0];
  const float* f_sem  = (const float*)d_in[1];
  const int*   seg    = (const int*)d_in[2];
  const float* s0_ws = (const float*)d_in[3];
  const float* s0_bs = (const float*)d_in[4];
  const float* s0_wg = (const float*)d_in[5];
  const float* s0_bg = (const float*)d_in[6];
  const float* s0_wb = (const float*)d_in[7];
  const float* s0_bb = (const float*)d_in[8];
  const float* s1_ws = (const float*)d_in[9];
  const float* s1_bs = (const float*)d_in[10];
  const float* s1_wg = (const float*)d_in[11];
  const float* s1_bg = (const float*)d_in[12];
  const float* s1_wb = (const float*)d_in[13];
  const float* s1_bb = (const float*)d_in[14];
  const float* s2_ws = (const float*)d_in[15];
  const float* s2_bs = (const float*)d_in[16];
  const float* s2_wg = (const float*)d_in[17];
  const float* s2_bg = (const float*)d_in[18];
  const float* s2_wb = (const float*)d_in[19];
  const float* s2_bb = (const float*)d_in[20];
  const float* w0 = (const float*)d_in[21];
  const float* b0 = (const float*)d_in[22];
  const float* w1 = (const float*)d_in[23];
  const float* b1 = (const float*)d_in[24];
  const float* w2 = (const float*)d_in[25];
  const float* b2 = (const float*)d_in[26];

  float* ws = (float*)d_ws;
  size_t o = 0;
  float* lnp   = ws + o; o += 512;                 // [4b][64][2] LN0 partials
  float* lnp2  = ws + o; o += 256;                 // [4b][32][2] LN2 partials
  float* y0pre = ws + o; o += 262144;              // [8cg][4b][8192]
  float* wbfp  = ws + o; o += 294912;              // [32ks][8][1152]
  float* bextp = ws + o; o += 256;                 // [32ks][8]
  bf16_t* hP   = (bf16_t*)(ws + o); o += 887808;   // 1,775,616 bf16
  float* sacc  = ws + o;                            // [3ks][3cid][4b][128][1024] fp32
  bf16_t* gamma0b = (bf16_t*)sacc;                  // aliases sacc (dead before convG)
  o += 4718592;
  float* sums   = ws + o; o += 98304;
  float* cnt    = ws + o; o += 256;
  bf16_t* smP   = (bf16_t*)(ws + o); o += 887808;  // 1,775,616 bf16
  bf16_t* wpkS  = (bf16_t*)(ws + o); o += 663552;  // 1,327,104 bf16
  bf16_t* wpkG0 = (bf16_t*)(ws + o); o += 958464;  // 1,916,928 bf16
  bf16_t* wpkG1 = (bf16_t*)(ws + o); o += 36864;
  bf16_t* wpkG2 = (bf16_t*)(ws + o); o += 36864;
  float* biasS  = ws + o; o += 384;
  float* biasG0 = ws + o; o += 1664;
  float* biasG1 = ws + o; o += 16;
  float* biasG2 = ws + o; o += 32;
  float* mu_r1  = ws + o; o += 8;
  float* y0     = ws + o; o += 32768;
  float* y1     = ws + o; o += 65536;
  float* g1out  = ws + o; o += 65536;
  float* g2out  = ws + o; o += 131072;

  hipLaunchKernelGGL(k_front, dim3(2016), dim3(256), 0, stream,
                     f_sem, seg, sums, cnt,
                     w0, s0_wb, s0_bb, b0,
                     s0_bs, s1_bs, s2_bs, s0_bg, s1_bg, s1_bb, s2_bg, s2_bb,
                     wbfp, bextp, biasS, biasG0, biasG1, biasG2,
                     x_main, lnp);
  hipLaunchKernelGGL(k_mid, dim3(5752), dim3(256), 0, stream,
                     sums, cnt, seg, smP,
                     s0_ws, s1_ws, s2_ws, s0_wg, wbfp, s1_wg, s1_wb, s2_wg, s2_wb,
                     wpkS, wpkG0, wpkG1, wpkG2);
  hipLaunchKernelGGL(k_convS, dim3(1152), dim3(256), 0, stream, smP, wpkS, sacc);
  hipLaunchKernelGGL(k_finS, dim3(192), dim3(256), 0, stream, sacc, biasS, hP);
  hipLaunchKernelGGL(k_convG, dim3(1152), dim3(256), 0, stream,
                     hP, wpkG0, wpkG1, wpkG2, biasG0, biasG1, biasG2,
                     gamma0b, g1out, g2out);
  hipLaunchKernelGGL(k_epi0p, dim3(32, NB, 8), dim3(256), 0, stream,
                     x_main, gamma0b, w0, lnp, y0pre);
  hipLaunchKernelGGL(k_fin0ln, dim3(NB), dim3(256), 0, stream, y0pre, gamma0b, bextp, y0, mu_r1);
  hipLaunchKernelGGL(k_epi1, dim3(32, NB), dim3(256), 0, stream, y0, g1out, w1, b1, mu_r1, y1, lnp2);
  hipLaunchKernelGGL(k_epi2, dim3(32, NB), dim3(256), 0, stream, y1, g2out, w2, b2, lnp2, (float*)d_out);
}